// Round 3
// 15973.514 us; speedup vs baseline: 2.1102x; 2.1102x over previous
//
#include <hip/hip_runtime.h>
#include <hip/hip_bf16.h>

// GRU: T=512, B=64, H=1024, L=2, gate order r|z|n (PyTorch).
// Round 6. History:
//  - r3 (PASSED, 33.7ms): CG grid.sync per step = 34us/step protocol cost
//    (256 serialized atomic arrivals + 2-phase spin + fences). All pipes idle.
//  - r4 (hang): hand-rolled sc0/sc1 asm coherence — wrong cache-bit semantics.
//  - r5 (wrong, absmax 2.9): relaxed agent atomic h loads/stores — flags
//    propagated (no hang) but h data read stale => relaxed atomic LOADS do
//    not reliably bypass stale L1/L2 for DATA on gfx950.
// This round: parallel flag-array barrier (the perf win) + the EXACT fence
// mechanism round 3 proved correct (compiler-emitted buffer_wbl2/buffer_inv
// via __threadfence), with plain cached h loads/stores:
//   release: __syncthreads (drains all waves' stores into L2 via vmcnt(0))
//            -> wave0 __threadfence() [wbl2: dirty h lines -> L3]
//            -> relaxed agent atomic flag store (proven to propagate, r5)
//   acquire: wave0 polls 64 group flags (1 slot/lane, relaxed agent loads)
//            -> __threadfence() [inv: L1+L2] -> __syncthreads -> plain h
//            loads miss and read fresh from L3.
// Barrier scope = 64 WGs (one q group), not 256: GRU rows are independent
// given x; WG(q,u) only needs h rows 16q..16q+16, produced by same-q WGs.
// 4 independent groups => less skew, 4x less flag traffic.
// Swizzle: q=(wg&7)>>1, u=(wg&1)*32+(wg>>3). wg%8==XCD (perf heuristic only;
// correctness rests on fences): each XCD owns a CONTIGUOUS 1KB column span
// per h row => all cross-XCD writeback boundaries are cacheline-aligned (no
// sub-line false sharing under wbl2), and x is fetched ~2x not 8x (r0's
// FETCH=540MB was x * 8 XCDs).
// Per-step L2 invalidate is cheap here: weights live in VGPRs all 512 steps,
// x[t] is single-use, h working set (128KB) stays L3-resident.
//
// Structure: per layer ONE cooperative kernel, 256 WGs x 256 thr (1 WG/CU).
// WG = (q: 16 batch rows, u: 16 units). Wave = K-quarter of both GEMMs; 48
// weight-row fragments resident in VGPRs all 512 steps. Per step: 48 MFMAs
// (16x16x32 f16) -> LDS reduce over 4 waves -> gate epilogue -> plain h
// store (ping-pong) -> fence + flag barrier (group q).

#define TT 512
#define BB 64
#define HH 1024

typedef short f16x8 __attribute__((ext_vector_type(8)));
typedef float f32x4 __attribute__((ext_vector_type(4)));

#define MFMA16(a, b, c) __builtin_amdgcn_mfma_f32_16x16x32_f16(a, b, c, 0, 0, 0)

#define AGENT_LD(p)     __hip_atomic_load((p), __ATOMIC_RELAXED, __HIP_MEMORY_SCOPE_AGENT)
#define AGENT_ST(p, v)  __hip_atomic_store((p), (v), __ATOMIC_RELAXED, __HIP_MEMORY_SCOPE_AGENT)

__device__ __forceinline__ unsigned short f2h(float f) {
    _Float16 h = (_Float16)f;   // RNE
    return *(unsigned short*)&h;
}

__global__ void cvt_f32_f16_x4(const float4* __restrict__ src,
                               ushort4* __restrict__ dst, int n4) {
    int i = blockIdx.x * blockDim.x + threadIdx.x;
    if (i >= n4) return;
    float4 v = src[i];
    ushort4 o;
    o.x = f2h(v.x); o.y = f2h(v.y); o.z = f2h(v.z); o.w = f2h(v.w);
    dst[i] = o;
}

__global__ void zero_u32(unsigned int* p, int n) {
    int i = blockIdx.x * blockDim.x + threadIdx.x;
    if (i < n) p[i] = 0u;
}

__global__ __launch_bounds__(256, 1) void gru_layer_k(
    const unsigned short* __restrict__ Wih,   // [3072][1024] f16 (layer slice)
    const unsigned short* __restrict__ Whh,   // [3072][1024] f16
    const float* __restrict__ bih,            // [3072]
    const float* __restrict__ bhh,            // [3072]
    const float* __restrict__ h0,             // [64][1024] fp32 (layer slice)
    const unsigned short* __restrict__ xin,   // [512][64][1024] f16
    unsigned short* hbuf0,                    // [64][1024] f16, pre-init to h0
    unsigned short* hbuf1,                    // [64][1024] f16 ping-pong
    unsigned short* ybf,                      // f16 y out (layer 1)
    float* yf32,                              // fp32 y out (layer 2 -> d_out)
    float* hn_out,                            // [64][1024] fp32 final h
    unsigned int* slots,                      // [256] barrier flags (monotonic)
    int tbase,                                // slot base: 0 (L0) / 512 (L1)
    int out_f32)
{
    const int tid  = threadIdx.x;
    const int wg   = blockIdx.x;
    // XCD-contiguous swizzle (perf heuristic; correctness from fences):
    // wg%8 -> XCD; XCD c handles q = c>>1, u in [32*(c&1), 32*(c&1)+32).
    const int x8   = wg & 7;
    const int q    = x8 >> 1;                      // batch group [0,4)
    const int u    = ((x8 & 1) << 5) | (wg >> 3);  // unit block [0,64)
    const int sidx = (q << 6) + u;                 // flag slot (group-major)
    const int wv   = tid >> 6;   // wave = K quarter
    const int lane = tid & 63;
    const int nm   = lane & 15;
    const int quad = lane >> 4;

    __shared__ float part[4][4][16][16];  // [wave][tile: r,z,nh,nx][b][j]
    __shared__ float cb[4][16];           // br, bz, bn_i, bn_h

    if (tid < 16) {
        int jgg = u * 16 + tid;
        cb[0][tid] = bih[jgg] + bhh[jgg];
        cb[1][tid] = bih[1024 + jgg] + bhh[1024 + jgg];
        cb[2][tid] = bih[2048 + jgg];
        cb[3][tid] = bhh[2048 + jgg];
    }
    const int bl = tid >> 4, jl = tid & 15;
    // fp32 running h for the z*h term: thread-private, exact carry.
    float hreg = h0[(size_t)(q * 16 + bl) * HH + u * 16 + jl];

    const int kbase = wv * 256 + quad * 8;

    // Resident weight fragments: 48 x f16x8 (unified VGPR/AGPR file).
    f16x8 brh[8], bzh[8], bnh[8], brx[8], bzx[8], bnx[8];
    {
        const unsigned short* wr = Whh + (size_t)(u * 16 + nm) * HH + kbase;
        const unsigned short* wz = wr + (size_t)1024 * HH;
        const unsigned short* wn = wz + (size_t)1024 * HH;
        const unsigned short* vr = Wih + (size_t)(u * 16 + nm) * HH + kbase;
        const unsigned short* vz = vr + (size_t)1024 * HH;
        const unsigned short* vn = vz + (size_t)1024 * HH;
#pragma unroll
        for (int kk = 0; kk < 8; ++kk) {
            brh[kk] = *(const f16x8*)(wr + kk * 32);
            bzh[kk] = *(const f16x8*)(wz + kk * 32);
            bnh[kk] = *(const f16x8*)(wn + kk * 32);
            brx[kk] = *(const f16x8*)(vr + kk * 32);
            bzx[kk] = *(const f16x8*)(vz + kk * 32);
            bnx[kk] = *(const f16x8*)(vn + kk * 32);
        }
    }
    __syncthreads();   // cb ready

    const size_t hoff = (size_t)(q * 16 + nm) * HH + kbase;
    const int bg = q * 16 + bl, jg = u * 16 + jl;
    const size_t hwid = (size_t)bg * HH + jg;

    for (int t = 0; t < TT; ++t) {
        const unsigned short* hrow = ((t & 1) ? hbuf1 : hbuf0) + hoff;
        unsigned short* hwr = (t & 1) ? hbuf0 : hbuf1;
        const unsigned short* xrow =
            xin + ((size_t)t * BB + q * 16 + nm) * HH + kbase;

        f32x4 ar  = {0.f, 0.f, 0.f, 0.f};
        f32x4 az  = {0.f, 0.f, 0.f, 0.f};
        f32x4 anh = {0.f, 0.f, 0.f, 0.f};
        f32x4 anx = {0.f, 0.f, 0.f, 0.f};
#pragma unroll
        for (int kk = 0; kk < 8; ++kk) {
            // Plain cached loads. Freshness: previous step's acquire fence
            // (buffer_inv) ran before this iteration (sync C orders it).
            f16x8 ah = *(const f16x8*)(hrow + kk * 32);
            f16x8 ax = *(const f16x8*)(xrow + kk * 32);
            ar  = MFMA16(ah, brh[kk], ar);
            az  = MFMA16(ah, bzh[kk], az);
            anh = MFMA16(ah, bnh[kk], anh);
            ar  = MFMA16(ax, brx[kk], ar);
            az  = MFMA16(ax, bzx[kk], az);
            anx = MFMA16(ax, bnx[kk], anx);
        }
        // C/D layout (m89-verified, dtype-independent): row(b)=quad*4+r, col(j)=lane&15.
#pragma unroll
        for (int r = 0; r < 4; ++r) {
            part[wv][0][quad * 4 + r][nm] = ar[r];
            part[wv][1][quad * 4 + r][nm] = az[r];
            part[wv][2][quad * 4 + r][nm] = anh[r];
            part[wv][3][quad * 4 + r][nm] = anx[r];
        }
        __syncthreads();   // A: partials ready

        float sr  = part[0][0][bl][jl] + part[1][0][bl][jl]
                  + part[2][0][bl][jl] + part[3][0][bl][jl];
        float sz  = part[0][1][bl][jl] + part[1][1][bl][jl]
                  + part[2][1][bl][jl] + part[3][1][bl][jl];
        float snh = part[0][2][bl][jl] + part[1][2][bl][jl]
                  + part[2][2][bl][jl] + part[3][2][bl][jl];
        float snx = part[0][3][bl][jl] + part[1][3][bl][jl]
                  + part[2][3][bl][jl] + part[3][3][bl][jl];

        float rg = 1.f / (1.f + __expf(-(sr + cb[0][jl])));
        float zg = 1.f / (1.f + __expf(-(sz + cb[1][jl])));
        float na = snx + cb[2][jl] + rg * (snh + cb[3][jl]);
        float ng = 1.f - 2.f / (1.f + __expf(2.f * na));  // tanh, overflow-safe
        float hnv = (1.f - zg) * ng + zg * hreg;
        hreg = hnv;

        unsigned short hb = f2h(hnv);
        hwr[hwid] = hb;                                  // plain, L2-cached
        size_t yi = ((size_t)t * BB + bg) * HH + jg;
        if (out_f32) yf32[yi] = hnv;
        else         ybf[yi] = hb;
        if (t == TT - 1) hn_out[hwid] = hnv;

        // --- group barrier (64 WGs sharing q), fence-based coherence ---
        __syncthreads();   // B: all 4 waves' stores drained into L2 (vmcnt(0))

        const unsigned int tgt = (unsigned int)(tbase + t + 1);
        if (wv == 0) {
            __threadfence();                 // release: wbl2 -> h lines at L3
            if (lane == 0) AGENT_ST(slots + sidx, tgt);
            // poll this q-group's 64 slots: one per lane
            const unsigned int* sl = slots + (q << 6) + lane;
            for (;;) {
                unsigned int s = AGENT_LD(sl);
                if (__all(s >= tgt)) break;
            }
            __threadfence();                 // acquire: inv L1+L2 -> fresh h
        }
        __syncthreads();   // C: release all waves into step t+1
    }
}

extern "C" void kernel_launch(void* const* d_in, const int* in_sizes, int n_in,
                              void* d_out, int out_size, void* d_ws, size_t ws_size,
                              hipStream_t stream) {
    const float* x   = (const float*)d_in[0];   // [512,64,1024]
    const float* h0  = (const float*)d_in[1];   // [2,64,1024]
    const float* Wih = (const float*)d_in[2];   // [2,3072,1024]
    const float* Whh = (const float*)d_in[3];   // [2,3072,1024]
    const float* bih = (const float*)d_in[4];   // [2,3072]
    const float* bhh = (const float*)d_in[5];   // [2,3072]
    float* out = (float*)d_out;                 // out [512,64,1024] ++ h_n [2,64,1024]

    char* ws = (char*)d_ws;
    unsigned short* x_f16  = (unsigned short*)(ws);               // 67,108,864 B
    unsigned short* ys1    = (unsigned short*)(ws + 67108864);    // 67,108,864 B
    unsigned short* Wih_h  = (unsigned short*)(ws + 134217728);   // 12,582,912 B
    unsigned short* Whh_h  = (unsigned short*)(ws + 146800640);   // 12,582,912 B
    unsigned short* hbuf0  = (unsigned short*)(ws + 159383552);   // 131,072 B
    unsigned short* hbuf1  = (unsigned short*)(ws + 159514624);   // 131,072 B
    unsigned int*   slots  = (unsigned int*)  (ws + 159645696);   // 1,024 B

    cvt_f32_f16_x4<<<32768, 256, 0, stream>>>((const float4*)x,   (ushort4*)x_f16, 8388608);
    cvt_f32_f16_x4<<<6144,  256, 0, stream>>>((const float4*)Wih, (ushort4*)Wih_h, 1572864);
    cvt_f32_f16_x4<<<6144,  256, 0, stream>>>((const float4*)Whh, (ushort4*)Whh_h, 1572864);
    cvt_f32_f16_x4<<<64,    256, 0, stream>>>((const float4*)h0,  (ushort4*)hbuf0, 16384);
    zero_u32<<<1, 256, 0, stream>>>(slots, 256);   // captured: re-zeroed each replay

    float* hn_base = out + (size_t)TT * BB * HH;   // 33,554,432

    {   // layer 0: x_f16 -> ys1 (f16), h_n[0]
        const unsigned short* a0 = Wih_h;
        const unsigned short* a1 = Whh_h;
        const float* a2 = bih;
        const float* a3 = bhh;
        const float* a4 = h0;
        const unsigned short* a5 = x_f16;
        unsigned short* a6 = hbuf0;
        unsigned short* a7 = hbuf1;
        unsigned short* a8 = ys1;
        float* a9 = out;        // unused (out_f32 = 0)
        float* a10 = hn_base;
        unsigned int* a11 = slots;
        int a12 = 0;            // tbase
        int a13 = 0;            // out_f32
        void* args[] = {&a0, &a1, &a2, &a3, &a4, &a5, &a6, &a7, &a8, &a9,
                        &a10, &a11, &a12, &a13};
        hipLaunchCooperativeKernel((void*)gru_layer_k, dim3(256), dim3(256),
                                   args, 0, stream);
    }

    cvt_f32_f16_x4<<<64, 256, 0, stream>>>((const float4*)(h0 + 65536),
                                           (ushort4*)hbuf0, 16384);

    {   // layer 1: ys1 -> d_out (fp32), h_n[1]
        const unsigned short* a0 = Wih_h + 3145728;
        const unsigned short* a1 = Whh_h + 3145728;
        const float* a2 = bih + 3072;
        const float* a3 = bhh + 3072;
        const float* a4 = h0 + 65536;
        const unsigned short* a5 = ys1;
        unsigned short* a6 = hbuf0;
        unsigned short* a7 = hbuf1;
        unsigned short* a8 = ys1;   // unused (out_f32 = 1)
        float* a9 = out;
        float* a10 = hn_base + 65536;
        unsigned int* a11 = slots;
        int a12 = 512;          // tbase: monotonic across layers, no reset
        int a13 = 1;            // out_f32
        void* args[] = {&a0, &a1, &a2, &a3, &a4, &a5, &a6, &a7, &a8, &a9,
                        &a10, &a11, &a12, &a13};
        hipLaunchCooperativeKernel((void*)gru_layer_k, dim3(256), dim3(256),
                                   args, 0, stream);
    }
}